// Round 4
// baseline (244.309 us; speedup 1.0000x reference)
//
#include <hip/hip_runtime.h>
#include <stdint.h>

#define NB   4
#define SEQ  4096
#define DIM  256
#define NROW (NB*SEQ)   // 16384

using bf16x8   = __attribute__((ext_vector_type(8))) __bf16;
using half8    = __attribute__((ext_vector_type(8))) _Float16;
using f32x4    = __attribute__((ext_vector_type(4))) float;
using f32x16   = __attribute__((ext_vector_type(16))) float;
using u32x4    = __attribute__((ext_vector_type(4))) unsigned int;
using ushort4t = __attribute__((ext_vector_type(4))) unsigned short;

__device__ __forceinline__ unsigned f2bf(float f){
    unsigned u = __builtin_bit_cast(unsigned, f);
    return (u + 0x7fffu + ((u >> 16) & 1u)) >> 16;   // RNE to bf16 bits
}
__device__ __forceinline__ float bf2f(unsigned b){
    return __builtin_bit_cast(float, b << 16);
}

#define MFMA(a,b,c)   __builtin_amdgcn_mfma_f32_16x16x32_bf16((a),(b),(c),0,0,0)
#define MFMAQK(a,b,c) __builtin_amdgcn_mfma_f32_32x32x16_f16((a),(b),(c),0,0,0)
#define MFMAPV(a,b,c) __builtin_amdgcn_mfma_f32_32x32x16_bf16((a),(b),(c),0,0,0)

// async global -> LDS, 16 B per lane. LDS dest = wave-uniform base + lane*16.
__device__ __forceinline__ void gld16(const void* g, void* l){
    __builtin_amdgcn_global_load_lds(
        (const __attribute__((address_space(1))) void*)g,
        (__attribute__((address_space(3))) void*)l, 16, 0, 0);
}

// ---------------------------------------------------------------------------
// Kernel 1: W[k][n] fp32 -> transposed split Wt_hi/Wt_lo[n][k] bf16
// ---------------------------------------------------------------------------
__global__ __launch_bounds__(256) void convert_w_kernel(
    const float* __restrict__ Wq, const float* __restrict__ Wk,
    const float* __restrict__ Wv,
    unsigned short* __restrict__ WtHi, unsigned short* __restrict__ WtLo)
{
    int mat = blockIdx.y;
    const float* W = (mat == 0) ? Wq : (mat == 1 ? Wk : Wv);
    int id = blockIdx.x * 256 + threadIdx.x;     // 0..65535
    int k = id >> 8, n = id & 255;
    float v = W[id];
    unsigned hi = f2bf(v);
    unsigned lo = f2bf(v - bf2f(hi));
    int o = mat * 65536 + n * 256 + k;            // transposed
    WtHi[o] = (unsigned short)hi;
    WtLo[o] = (unsigned short)lo;
}

// ---------------------------------------------------------------------------
// Kernel 2: fused QKV projection (3-term bf16 split, fp32 accum — accurate).
// Epilogue emits: Qf, Kf as fp16 [row][256], Vt as plain-transposed bf16
// [b][d][s].
// ---------------------------------------------------------------------------
__global__ __launch_bounds__(256) void proj_kernel(
    const float* __restrict__ x,
    const unsigned short* __restrict__ WtHi, const unsigned short* __restrict__ WtLo,
    const float* __restrict__ bq, const float* __restrict__ bk,
    const float* __restrict__ bv,
    _Float16* __restrict__ Qf, _Float16* __restrict__ Kf,
    unsigned short* __restrict__ Vt)
{
    const int tid = threadIdx.x, lane = tid & 63, wid = tid >> 6;
    const int g = lane >> 4, q16 = lane & 15;
    const int mbase = blockIdx.x * 64 + wid * 16;
    const int nh = blockIdx.y;

    f32x4 acc[3][8];
    #pragma unroll
    for (int m = 0; m < 3; m++)
        #pragma unroll
        for (int n = 0; n < 8; n++) acc[m][n] = f32x4{0.f, 0.f, 0.f, 0.f};

    const float* xr = x + (mbase + q16) * DIM;

    for (int kc = 0; kc < 8; kc++) {
        const float* p = xr + kc * 32 + 8 * g;
        f32x4 va = *(const f32x4*)p;
        f32x4 vb = *(const f32x4*)(p + 4);
        float fv[8] = {va[0], va[1], va[2], va[3], vb[0], vb[1], vb[2], vb[3]};
        unsigned hw[4], lw[4];
        #pragma unroll
        for (int i = 0; i < 4; i++) {
            unsigned h0 = f2bf(fv[2*i]),              h1 = f2bf(fv[2*i+1]);
            unsigned l0 = f2bf(fv[2*i]   - bf2f(h0)), l1 = f2bf(fv[2*i+1] - bf2f(h1));
            hw[i] = h0 | (h1 << 16);
            lw[i] = l0 | (l1 << 16);
        }
        bf16x8 ahi = __builtin_bit_cast(bf16x8, u32x4{hw[0], hw[1], hw[2], hw[3]});
        bf16x8 alo = __builtin_bit_cast(bf16x8, u32x4{lw[0], lw[1], lw[2], lw[3]});

        #pragma unroll
        for (int mat = 0; mat < 3; mat++) {
            #pragma unroll
            for (int nt = 0; nt < 8; nt++) {
                int ncol = nh * 128 + nt * 16 + q16;
                int off  = mat * 65536 + ncol * 256 + kc * 32 + 8 * g;
                bf16x8 bh = *(const bf16x8*)(WtHi + off);
                bf16x8 bl = *(const bf16x8*)(WtLo + off);
                acc[mat][nt] = MFMA(ahi, bh, acc[mat][nt]);
                acc[mat][nt] = MFMA(ahi, bl, acc[mat][nt]);
                acc[mat][nt] = MFMA(alo, bh, acc[mat][nt]);
            }
        }
    }

    #pragma unroll
    for (int nt = 0; nt < 8; nt++) {
        int ncol = nh * 128 + nt * 16 + q16;
        {   // Q -> fp16
            float bb = bq[ncol];
            f32x4 c = acc[0][nt];
            #pragma unroll
            for (int r = 0; r < 4; r++)
                Qf[(size_t)(mbase + 4*g + r) * DIM + ncol] = (_Float16)(c[r] + bb);
        }
        {   // K -> fp16
            float bb = bk[ncol];
            f32x4 c = acc[1][nt];
            #pragma unroll
            for (int r = 0; r < 4; r++)
                Kf[(size_t)(mbase + 4*g + r) * DIM + ncol] = (_Float16)(c[r] + bb);
        }
        {   // V -> plain transposed bf16 Vt[b][d][s]
            float bb = bv[ncol];
            f32x4 c = acc[2][nt];
            ushort4t pk;
            #pragma unroll
            for (int r = 0; r < 4; r++) pk[r] = (unsigned short)f2bf(c[r] + bb);
            int m0 = mbase + 4 * g;
            int bat = m0 >> 12, s0 = m0 & 4095;
            *(ushort4t*)(Vt + (size_t)(bat * DIM + ncol) * SEQ + s0) = pk;
        }
    }
}

// ---------------------------------------------------------------------------
// Kernel 3: flash attention, 32x32 MFMA tiles, fp16 QK^T, bf16 PV.
// Block: 4 waves x 32 q-rows = 128 rows. grid (128 qtiles, 4 kv-splits).
// Per split 1024 kv = 32 chunks of 32. Double-buffered async staging.
// LDS/buffer: K fp16 [32][256] 16KB + Vt bf16 [256][32] 16KB -> 64KB total.
// P->PV via cvt_pk_bf16 + permlane32_swap (zero cross-lane shuffles).
// ---------------------------------------------------------------------------
#define KLDS  0
#define VLDS  16384
#define BUFSZ 32768

__global__ __launch_bounds__(256, 2) void flash_kernel(
    const _Float16* __restrict__ Qf, const _Float16* __restrict__ Kf,
    const unsigned short* __restrict__ Vt,
    float* __restrict__ o0, unsigned short* __restrict__ o1,
    unsigned short* __restrict__ o2, unsigned short* __restrict__ o3,
    float2* __restrict__ ml0, float2* __restrict__ ml1,
    float2* __restrict__ ml2, float2* __restrict__ ml3)
{
    __shared__ __align__(16) unsigned char smem[65536];

    const int tid = threadIdx.x, lane = tid & 63, wid = tid >> 6;
    const int r32 = lane & 31, h = lane >> 5;
    const int qrow0 = blockIdx.x * 128;
    const int b = qrow0 >> 12;
    const int split = blockIdx.y;
    const int kvbase = split * 1024;

    // --- Q fragments: B-operand, col q = r32, k = 16s + 8h + j ---
    half8 qf[16];
    {
        const _Float16* qp = Qf + (size_t)(qrow0 + wid * 32 + r32) * DIM;
        #pragma unroll
        for (int s = 0; s < 16; s++)
            qf[s] = *(const half8*)(qp + s * 16 + h * 8);
    }

    f32x16 o[8];
    #pragma unroll
    for (int i = 0; i < 8; i++)
        #pragma unroll
        for (int j = 0; j < 16; j++) o[i][j] = 0.f;
    float m_run = -3.0e38f, l_run = 0.f;

    // ---- staging: 8 x global_load_lds per wave per chunk ----
    auto stage = [&](int chunk, int buf) {
        const int kv0 = kvbase + chunk * 32;
        unsigned char* base = smem + buf * BUFSZ;
        #pragma unroll
        for (int i = 0; i < 4; i++) {
            const int t = wid * 4 + i;
            // K fp16 [32 rows][512B]; instr t covers rows 2t,2t+1
            const int krow = 2 * t + h;
            const int ksl  = (lane & 31) ^ (krow & 7);
            gld16(Kf + (size_t)(b * SEQ + kvbase + chunk * 32 + krow) * DIM + ksl * 8,
                  base + KLDS + t * 1024);
            // V bf16 [256 d][64B]; instr t covers d 16t..16t+15
            const int d  = 16 * t + (lane >> 2);
            const int vsl = (lane & 3) ^ (d & 3);
            gld16(Vt + (size_t)(b * DIM + d) * SEQ + kv0 + vsl * 8,
                  base + VLDS + t * 1024);
        }
    };

    stage(0, 0);
    __syncthreads();

    for (int c = 0; c < 32; c++) {
        const int bf = c & 1;
        if (c + 1 < 32) stage(c + 1, bf ^ 1);

        const unsigned char* kb = smem + bf * BUFSZ;

        // ---- QK^T: A = K (rows=kv), B = Q (cols=q); 2 acc chains ----
        f32x16 acc0, acc1;
        #pragma unroll
        for (int j = 0; j < 16; j++) { acc0[j] = 0.f; acc1[j] = 0.f; }
        __builtin_amdgcn_s_setprio(1);
        #pragma unroll
        for (int s = 0; s < 16; s += 2) {
            const int off0 = r32 * 512 + (((2 * s + h)     ^ (r32 & 7)) * 16);
            const int off1 = r32 * 512 + (((2 * s + 2 + h) ^ (r32 & 7)) * 16);
            half8 kf0 = *(const half8*)(kb + KLDS + off0);
            half8 kf1 = *(const half8*)(kb + KLDS + off1);
            acc0 = MFMAQK(kf0, qf[s],     acc0);
            acc1 = MFMAQK(kf1, qf[s + 1], acc1);
        }
        __builtin_amdgcn_s_setprio(0);
        f32x16 sc = acc0 + acc1;
        // lane holds S[kv=(r&3)+8*(r>>2)+4h][q=r32] in sc[r]

        // ---- online softmax (per q-column; halves reduced via xor-32) ----
        float pm = sc[0];
        #pragma unroll
        for (int j = 1; j < 16; j++) pm = fmaxf(pm, sc[j]);
        pm = fmaxf(pm, __shfl_xor(pm, 32, 64));
        const bool defer = __all(pm <= m_run + 8.0f) != 0;
        const float m_new = defer ? m_run : fmaxf(m_run, pm);
        const float scale = defer ? 1.0f : __expf(m_run - m_new);
        float e[16];
        float ps = 0.f;
        #pragma unroll
        for (int j = 0; j < 16; j++) { e[j] = __expf(sc[j] - m_new); ps += e[j]; }
        ps += __shfl_xor(ps, 32, 64);
        l_run = l_run * scale + ps;
        m_run = m_new;

        // ---- P -> bf16 B-fragments via cvt_pk + permlane32_swap ----
        unsigned w[8];
        #pragma unroll
        for (int t = 0; t < 8; t++)
            asm("v_cvt_pk_bf16_f32 %0, %1, %2"
                : "=v"(w[t]) : "v"(e[2 * t]), "v"(e[2 * t + 1]));
        asm volatile("v_permlane32_swap_b32 %0, %1" : "+v"(w[0]), "+v"(w[2]));
        asm volatile("v_permlane32_swap_b32 %0, %1" : "+v"(w[1]), "+v"(w[3]));
        asm volatile("v_permlane32_swap_b32 %0, %1" : "+v"(w[4]), "+v"(w[6]));
        asm volatile("v_permlane32_swap_b32 %0, %1" : "+v"(w[5]), "+v"(w[7]));
        bf16x8 pA = __builtin_bit_cast(bf16x8, u32x4{w[0], w[1], w[2], w[3]});
        bf16x8 pB = __builtin_bit_cast(bf16x8, u32x4{w[4], w[5], w[6], w[7]});

        // ---- PV: A = V^T (rows=d, k=kv), B = P; rescale lane-local ----
        const unsigned char* vb = kb + VLDS;
        __builtin_amdgcn_s_setprio(1);
        #pragma unroll
        for (int dt = 0; dt < 8; dt++) {
            const int d = dt * 32 + r32;
            bf16x8 v0 = *(const bf16x8*)(vb + d * 64 + (( h      ^ (d & 3)) * 16));
            bf16x8 v1 = *(const bf16x8*)(vb + d * 64 + (((2 + h) ^ (d & 3)) * 16));
            f32x16 oo = o[dt];
            if (!defer) {
                #pragma unroll
                for (int j = 0; j < 16; j++) oo[j] *= scale;
            }
            oo = MFMAPV(v0, pA, oo);
            oo = MFMAPV(v1, pB, oo);
            o[dt] = oo;
        }
        __builtin_amdgcn_s_setprio(0);

        __syncthreads();   // drains vmcnt: prefetch landed; buffers reusable
    }

    // ---- m,l store (halves hold identical values; h==0 writes) ----
    if (h == 0) {
        float2 ml = float2{m_run, l_run};
        float2* mlp = (split == 0) ? ml0 : (split == 1) ? ml1
                    : (split == 2) ? ml2 : ml3;
        mlp[qrow0 + wid * 32 + r32] = ml;
    }

    // ---- epilogue: LDS transpose (64-d quarters) + coalesced store ----
    float* T = (float*)smem;   // [128 q][65] f32 = 33 KB
    for (int Z = 0; Z < 4; Z++) {
        __syncthreads();
        #pragma unroll
        for (int u = 0; u < 2; u++) {
            const int dt = 2 * Z + u;
            #pragma unroll
            for (int r = 0; r < 16; r++) {
                const int dloc = (r & 3) + 8 * (r >> 2) + 4 * h;
                T[(wid * 32 + r32) * 65 + u * 32 + dloc] = o[dt][r];
            }
        }
        __syncthreads();
        const int qloc = tid >> 1, dof = (tid & 1) * 32;
        const float* tr = T + qloc * 65 + dof;
        const size_t gbase = (size_t)(qrow0 + qloc) * DIM + Z * 64 + dof;
        if (split == 0) {
            #pragma unroll
            for (int j = 0; j < 32; j += 4)
                *(f32x4*)(o0 + gbase + j) = *(const f32x4*)(tr + j);
        } else {
            unsigned short* oP = (split == 1) ? o1 : (split == 2) ? o2 : o3;
            #pragma unroll
            for (int j = 0; j < 32; j += 4) {
                f32x4 v = *(const f32x4*)(tr + j);
                ushort4t pk;
                #pragma unroll
                for (int r2 = 0; r2 < 4; r2++) pk[r2] = (unsigned short)f2bf(v[r2]);
                *(ushort4t*)(oP + gbase + j) = pk;
            }
        }
    }
}

// ---------------------------------------------------------------------------
// Kernel 4: merge the four kv-split partials + residual.
// ---------------------------------------------------------------------------
__global__ __launch_bounds__(256) void combine_kernel(
    const float* __restrict__ o0, const unsigned short* __restrict__ o1,
    const unsigned short* __restrict__ o2, const unsigned short* __restrict__ o3,
    const float2* __restrict__ ml0, const float2* __restrict__ ml1,
    const float2* __restrict__ ml2, const float2* __restrict__ ml3,
    const float* __restrict__ x, float* __restrict__ out)
{
    int row = blockIdx.x * 4 + (threadIdx.x >> 6);
    int c0  = (threadIdx.x & 63) * 4;
    float2 A = ml0[row], B = ml1[row], C = ml2[row], D = ml3[row];
    float M  = fmaxf(fmaxf(A.x, B.x), fmaxf(C.x, D.x));
    float w0 = __expf(A.x - M), w1 = __expf(B.x - M);
    float w2 = __expf(C.x - M), w3 = __expf(D.x - M);
    float inv = 1.0f / (w0 * A.y + w1 * B.y + w2 * C.y + w3 * D.y);
    size_t base = (size_t)row * DIM + c0;
    f32x4    v0 = *(const f32x4*)(o0 + base);
    ushort4t u1 = *(const ushort4t*)(o1 + base);
    ushort4t u2 = *(const ushort4t*)(o2 + base);
    ushort4t u3 = *(const ushort4t*)(o3 + base);
    f32x4    xr = *(const f32x4*)(x + base);
    f32x4 res;
    #pragma unroll
    for (int j = 0; j < 4; j++)
        res[j] = (w0 * v0[j] + w1 * bf2f((unsigned)u1[j])
                + w2 * bf2f((unsigned)u2[j]) + w3 * bf2f((unsigned)u3[j])) * inv
                + xr[j];
    *(f32x4*)(out + base) = res;
}

// ---------------------------------------------------------------------------
extern "C" void kernel_launch(void* const* d_in, const int* in_sizes, int n_in,
                              void* d_out, int out_size, void* d_ws, size_t ws_size,
                              hipStream_t stream)
{
    const float* x  = (const float*)d_in[0];
    const float* Wq = (const float*)d_in[1];
    const float* bq = (const float*)d_in[2];
    const float* Wk = (const float*)d_in[3];
    const float* bk = (const float*)d_in[4];
    const float* Wv = (const float*)d_in[5];
    const float* bv = (const float*)d_in[6];
    float* out = (float*)d_out;

    unsigned char* ws = (unsigned char*)d_ws;
    _Float16*       Qf   = (_Float16*)(ws);                      //  8 MB
    _Float16*       Kf   = (_Float16*)(ws +  8388608);           //  8 MB
    unsigned short* Vt   = (unsigned short*)(ws + 16777216);     // 16 MB
    unsigned short* WtHi = (unsigned short*)(ws + 33554432);     // 384 KB
    unsigned short* WtLo = (unsigned short*)(ws + 33947648);     // 384 KB
    unsigned short* O1   = (unsigned short*)(ws + 34340864);     //  8 MB
    unsigned short* O2   = (unsigned short*)(ws + 42729472);     //  8 MB
    unsigned short* O3   = (unsigned short*)(ws + 51118080);     //  8 MB
    float2*         ML0  = (float2*)       (ws + 59506688);
    float2*         ML1  = (float2*)       (ws + 59637760);
    float2*         ML2  = (float2*)       (ws + 59768832);
    float2*         ML3  = (float2*)       (ws + 59899904);
    // total ws use: 60,030,976 bytes

    convert_w_kernel<<<dim3(256, 3), 256, 0, stream>>>(Wq, Wk, Wv, WtHi, WtLo);
    proj_kernel<<<dim3(256, 2), 256, 0, stream>>>(x, WtHi, WtLo, bq, bk, bv,
                                                  Qf, Kf, Vt);
    flash_kernel<<<dim3(128, 4), 256, 0, stream>>>(Qf, Kf, Vt,
                                                   out, O1, O2, O3,
                                                   ML0, ML1, ML2, ML3);
    combine_kernel<<<4096, 256, 0, stream>>>(out, O1, O2, O3,
                                             ML0, ML1, ML2, ML3, x, out);
}